// Round 1
// baseline (478.349 us; speedup 1.0000x reference)
//
#include <hip/hip_runtime.h>
#include <hip/hip_bf16.h>

#define B_  8
#define D_  192
#define H_  64
#define W_  64
#define L_  4096
#define K_  4
#define N_  16
#define R_  6
#define C_  38   // R + 2N
#define CP  40   // padded x_dbl row (floats)
#define CL_ 128  // scan chunk length
#define NC_ 32   // number of chunks (L_/CL_)

using bf16 = __hip_bfloat16;

static __device__ __forceinline__ float softplus_f(float x) {
    // matches jax.nn.softplus: max(x,0) + log1p(exp(-|x|))
    return fmaxf(x, 0.f) + __logf(1.f + __expf(-fabsf(x)));
}

// ---------------------------------------------------------------------------
// Kernel 1: transpose x (B,D,L) -> xp0 (B,L,D) [row-major scan order]
//                            and xp1 (B,L1,D) [col-major scan order],
// where l1 = w*H + h for spatial p = h*W + w.
// ---------------------------------------------------------------------------
__global__ __launch_bounds__(256) void k_transpose(const float* __restrict__ x,
                                                   float* __restrict__ xp0,
                                                   float* __restrict__ xp1) {
    __shared__ float tile[32][33];
    int bi = blockIdx.x;
    int pg = bi & 127;          // L/32 tiles
    int dg = (bi >> 7) % 6;     // D/32 tiles
    int b  = bi / (128 * 6);
    int tx = threadIdx.x & 31;
    int ty = threadIdx.x >> 5;  // 0..7
    size_t xbase = (size_t)b * D_ * L_;
    #pragma unroll
    for (int i = 0; i < 4; i++) {
        int d = dg * 32 + ty + i * 8;
        tile[ty + i * 8][tx] = x[xbase + (size_t)d * L_ + pg * 32 + tx];
    }
    __syncthreads();
    #pragma unroll
    for (int i = 0; i < 4; i++) {
        int p = pg * 32 + ty + i * 8;
        float v = tile[tx][ty + i * 8];
        int d = dg * 32 + tx;
        xp0[((size_t)b * L_ + p) * D_ + d] = v;
        int hh = p >> 6, ww = p & 63;
        int r = ww * 64 + hh;   // l1 index
        xp1[((size_t)b * L_ + r) * D_ + d] = v;
    }
}

// ---------------------------------------------------------------------------
// Kernel 2: projection x_dbl[b,k,l,c] = sum_d xs[b,k,d,l] * W[k,c,d]
// One thread per scan position; 38 accumulators in registers; W via uniform
// (scalar-promotable) loads; x row via per-thread float4 global loads.
// ---------------------------------------------------------------------------
__global__ __launch_bounds__(256) void k_proj(const float* __restrict__ xp0,
                                              const float* __restrict__ xp1,
                                              const float* __restrict__ Wp,   // (K,38,192)
                                              float* __restrict__ xdbl) {     // (B,K,L,CP)
    int blk  = blockIdx.x;
    int tile = blk & 15;            // L/256 tiles
    int bk   = blk >> 4;
    int k    = bk & 3;
    int b    = bk >> 2;
    int l    = tile * 256 + (int)threadIdx.x;
    int lu   = (k < 2) ? l : (L_ - 1 - l);
    const float* xp = (k & 1) ? xp1 : xp0;
    const float4* xrow = (const float4*)(xp + ((size_t)b * L_ + lu) * D_);
    const float4* Wb   = (const float4*)(Wp + (size_t)k * C_ * D_);
    float acc[C_];
    #pragma unroll
    for (int c = 0; c < C_; c++) acc[c] = 0.f;
    for (int kk = 0; kk < 48; kk += 2) {   // 48 float4 per 192-f32 row
        float4 x0 = xrow[kk];
        float4 x1 = xrow[kk + 1];
        #pragma unroll
        for (int c = 0; c < C_; c++) {
            float4 w0 = Wb[c * 48 + kk];
            float4 w1 = Wb[c * 48 + kk + 1];
            acc[c] = fmaf(x0.x, w0.x, acc[c]); acc[c] = fmaf(x0.y, w0.y, acc[c]);
            acc[c] = fmaf(x0.z, w0.z, acc[c]); acc[c] = fmaf(x0.w, w0.w, acc[c]);
            acc[c] = fmaf(x1.x, w1.x, acc[c]); acc[c] = fmaf(x1.y, w1.y, acc[c]);
            acc[c] = fmaf(x1.z, w1.z, acc[c]); acc[c] = fmaf(x1.w, w1.w, acc[c]);
        }
    }
    float* orow = xdbl + ((size_t)bk * L_ + l) * CP;
    #pragma unroll
    for (int c = 0; c < C_; c++) orow[c] = acc[c];
}

// ---------------------------------------------------------------------------
// Kernel 3 (pass 1): per-chunk partial scan from h=0. Stores chunk decay
// P = exp(A * sum(delta)) and local end-state Hloc, both bf16.
// Block = (b,k,chunk), thread = d channel, 16 states in registers.
// ---------------------------------------------------------------------------
__global__ __launch_bounds__(192) void k_pass1(const float* __restrict__ xdbl,
                                               const float* __restrict__ xp0,
                                               const float* __restrict__ xp1,
                                               const float* __restrict__ dtw,   // (K,D,R)
                                               const float* __restrict__ dtb,   // (K,D)
                                               const float* __restrict__ Alog,  // (K*D,N)
                                               bf16* __restrict__ Pst,
                                               bf16* __restrict__ Hloc) {
    int blk = blockIdx.x;
    int c   = blk & (NC_ - 1);
    int bk  = blk >> 5;
    int k   = bk & 3;
    int b   = bk >> 2;
    int d   = threadIdx.x;

    float A[N_];
    #pragma unroll
    for (int n = 0; n < N_; n++) A[n] = -__expf(Alog[((size_t)(k * D_ + d)) * N_ + n]);
    float wr[R_];
    #pragma unroll
    for (int r = 0; r < R_; r++) wr[r] = dtw[(k * D_ + d) * R_ + r];
    float bias = dtb[k * D_ + d];
    const float* xp = (k & 1) ? xp1 : xp0;

    float h[N_];
    #pragma unroll
    for (int n = 0; n < N_; n++) h[n] = 0.f;
    float S = 0.f;
    const float4* rb = (const float4*)(xdbl + ((size_t)bk * L_ + c * CL_) * CP);

    for (int s = 0; s < CL_; s++) {
        const float4* r4 = rb + s * (CP / 4);
        float4 q0 = r4[0], q1 = r4[1], q2 = r4[2], q3 = r4[3], q4 = r4[4], q5 = r4[5];
        float dpre = bias + wr[0]*q0.x + wr[1]*q0.y + wr[2]*q0.z + wr[3]*q0.w
                          + wr[4]*q1.x + wr[5]*q1.y;
        float delta = softplus_f(dpre);
        int l  = c * CL_ + s;
        int lu = (k < 2) ? l : (L_ - 1 - l);
        float u  = xp[((size_t)b * L_ + lu) * D_ + d];
        float du = delta * u;
        S += delta;
        float Bv[N_] = {q1.z,q1.w,q2.x,q2.y,q2.z,q2.w,q3.x,q3.y,
                        q3.z,q3.w,q4.x,q4.y,q4.z,q4.w,q5.x,q5.y};
        #pragma unroll
        for (int n = 0; n < N_; n++) {
            float dA = __expf(delta * A[n]);
            h[n] = fmaf(dA, h[n], du * Bv[n]);
        }
    }
    size_t o = ((size_t)blk * D_ + d) * N_;   // blk == bk*NC_ + c
    #pragma unroll
    for (int n = 0; n < N_; n++) {
        Pst[o + n]  = __float2bfloat16(__expf(A[n] * S));
        Hloc[o + n] = __float2bfloat16(h[n]);
    }
}

// ---------------------------------------------------------------------------
// Kernel 4 (pass 2): chunk-prefix scan over NC_ chunks per (b,k,d,n).
// Hin[c] = state entering chunk c.
// ---------------------------------------------------------------------------
__global__ __launch_bounds__(256) void k_pass2(const bf16* __restrict__ Pst,
                                               const bf16* __restrict__ Hloc,
                                               bf16* __restrict__ Hin) {
    int idx = blockIdx.x * 256 + threadIdx.x;   // over B*K*D*N
    int bk  = idx / (D_ * N_);
    int dn  = idx % (D_ * N_);
    float hh = 0.f;
    for (int c = 0; c < NC_; c++) {
        size_t o = ((size_t)bk * NC_ + c) * (D_ * N_) + dn;
        Hin[o] = __float2bfloat16(hh);
        hh = __bfloat162float(Pst[o]) * hh + __bfloat162float(Hloc[o]);
    }
}

// ---------------------------------------------------------------------------
// Kernel 5 (pass 3): recompute chunk scan with true h0, emit
// ys[b,k,l,d] = C_l . h_l + u * Ds   (bf16)
// ---------------------------------------------------------------------------
__global__ __launch_bounds__(192) void k_pass3(const float* __restrict__ xdbl,
                                               const float* __restrict__ xp0,
                                               const float* __restrict__ xp1,
                                               const float* __restrict__ dtw,
                                               const float* __restrict__ dtb,
                                               const float* __restrict__ Alog,
                                               const float* __restrict__ Dsk,  // (K*D,)
                                               const bf16* __restrict__ Hin,
                                               bf16* __restrict__ ys) {        // (B,K,L,D)
    int blk = blockIdx.x;
    int c   = blk & (NC_ - 1);
    int bk  = blk >> 5;
    int k   = bk & 3;
    int b   = bk >> 2;
    int d   = threadIdx.x;

    float A[N_];
    #pragma unroll
    for (int n = 0; n < N_; n++) A[n] = -__expf(Alog[((size_t)(k * D_ + d)) * N_ + n]);
    float wr[R_];
    #pragma unroll
    for (int r = 0; r < R_; r++) wr[r] = dtw[(k * D_ + d) * R_ + r];
    float bias = dtb[k * D_ + d];
    float DsV  = Dsk[k * D_ + d];
    const float* xp = (k & 1) ? xp1 : xp0;

    float h[N_];
    size_t o = ((size_t)blk * D_ + d) * N_;
    #pragma unroll
    for (int n = 0; n < N_; n++) h[n] = __bfloat162float(Hin[o + n]);

    const float4* rb = (const float4*)(xdbl + ((size_t)bk * L_ + c * CL_) * CP);

    for (int s = 0; s < CL_; s++) {
        const float4* r4 = rb + s * (CP / 4);
        float4 q0 = r4[0], q1 = r4[1], q2 = r4[2], q3 = r4[3], q4 = r4[4];
        float4 q5 = r4[5], q6 = r4[6], q7 = r4[7], q8 = r4[8], q9 = r4[9];
        float dpre = bias + wr[0]*q0.x + wr[1]*q0.y + wr[2]*q0.z + wr[3]*q0.w
                          + wr[4]*q1.x + wr[5]*q1.y;
        float delta = softplus_f(dpre);
        int l  = c * CL_ + s;
        int lu = (k < 2) ? l : (L_ - 1 - l);
        float u  = xp[((size_t)b * L_ + lu) * D_ + d];
        float du = delta * u;
        float Bv[N_] = {q1.z,q1.w,q2.x,q2.y,q2.z,q2.w,q3.x,q3.y,
                        q3.z,q3.w,q4.x,q4.y,q4.z,q4.w,q5.x,q5.y};
        float Cv[N_] = {q5.z,q5.w,q6.x,q6.y,q6.z,q6.w,q7.x,q7.y,
                        q7.z,q7.w,q8.x,q8.y,q8.z,q8.w,q9.x,q9.y};
        float y = 0.f;
        #pragma unroll
        for (int n = 0; n < N_; n++) {
            float dA = __expf(delta * A[n]);
            h[n] = fmaf(dA, h[n], du * Bv[n]);
            y = fmaf(h[n], Cv[n], y);
        }
        ys[((size_t)bk * L_ + l) * D_ + d] = __float2bfloat16(y + u * DsV);
    }
}

// ---------------------------------------------------------------------------
// Kernel 6: cross-merge (4 directions) + LayerNorm over D, output (B,H,W,D)
// ---------------------------------------------------------------------------
__global__ __launch_bounds__(192) void k_merge_ln(const bf16* __restrict__ ys,
                                                  const float* __restrict__ gw,
                                                  const float* __restrict__ gb,
                                                  float* __restrict__ out) {
    int p = blockIdx.x & (L_ - 1);
    int b = blockIdx.x >> 12;     // L_ = 4096
    int d = threadIdx.x;
    int hh = p >> 6, ww = p & 63;
    int l1 = ww * 64 + hh;
    size_t base = (size_t)b * K_ * L_ * D_;
    float v = __bfloat162float(ys[base + ((size_t)0 * L_ + p) * D_ + d])
            + __bfloat162float(ys[base + ((size_t)2 * L_ + (L_ - 1 - p)) * D_ + d])
            + __bfloat162float(ys[base + ((size_t)1 * L_ + l1) * D_ + d])
            + __bfloat162float(ys[base + ((size_t)3 * L_ + (L_ - 1 - l1)) * D_ + d]);
    float s1 = v, s2 = v * v;
    #pragma unroll
    for (int off = 32; off; off >>= 1) {
        s1 += __shfl_down(s1, off);
        s2 += __shfl_down(s2, off);
    }
    __shared__ float aS[3], aQ[3];
    int wid = d >> 6, lane = d & 63;
    if (lane == 0) { aS[wid] = s1; aQ[wid] = s2; }
    __syncthreads();
    float ts1 = aS[0] + aS[1] + aS[2];
    float ts2 = aQ[0] + aQ[1] + aQ[2];
    float mean = ts1 * (1.f / 192.f);
    float var  = ts2 * (1.f / 192.f) - mean * mean;
    float inv  = rsqrtf(var + 1e-5f);
    out[((size_t)b * L_ + p) * D_ + d] = (v - mean) * inv * gw[d] + gb[d];
}

// ---------------------------------------------------------------------------
extern "C" void kernel_launch(void* const* d_in, const int* in_sizes, int n_in,
                              void* d_out, int out_size, void* d_ws, size_t ws_size,
                              hipStream_t stream) {
    const float* x    = (const float*)d_in[0];
    const float* Wp   = (const float*)d_in[1];
    const float* dtw  = (const float*)d_in[2];
    const float* dtb  = (const float*)d_in[3];
    const float* Alog = (const float*)d_in[4];
    const float* Dsk  = (const float*)d_in[5];
    const float* gw   = (const float*)d_in[6];
    const float* gb   = (const float*)d_in[7];
    float* out = (float*)d_out;

    char* ws = (char*)d_ws;
    const size_t S1 = (size_t)B_ * L_ * D_ * 4;           // 25.2 MB (xp0 / xp1)
    const size_t Sx = (size_t)B_ * K_ * L_ * CP * 4;      // 21.0 MB (xdbl)
    const size_t Ss = (size_t)B_ * K_ * NC_ * D_ * N_ * 2;// 6.3 MB  (P / Hloc / Hin)
    float* xp0  = (float*)(ws);
    float* xp1  = (float*)(ws + S1);
    float* xdbl = (float*)(ws + 2 * S1);
    bf16*  Pst  = (bf16*)(ws + 2 * S1 + Sx);
    bf16*  Hloc = (bf16*)(ws + 2 * S1 + Sx + Ss);
    bf16*  Hin  = (bf16*)(ws + 2 * S1 + Sx + 2 * Ss);
    bf16*  ys   = (bf16*)(ws + 2 * S1 + Sx + 3 * Ss);     // 50.3 MB
    // total ws use: ~140.5 MB

    k_transpose<<<B_ * 6 * 128, 256, 0, stream>>>(x, xp0, xp1);
    k_proj<<<B_ * K_ * (L_ / 256), 256, 0, stream>>>(xp0, xp1, Wp, xdbl);
    k_pass1<<<B_ * K_ * NC_, 192, 0, stream>>>(xdbl, xp0, xp1, dtw, dtb, Alog, Pst, Hloc);
    k_pass2<<<(B_ * K_ * D_ * N_) / 256, 256, 0, stream>>>(Pst, Hloc, Hin);
    k_pass3<<<B_ * K_ * NC_, 192, 0, stream>>>(xdbl, xp0, xp1, dtw, dtb, Alog, Dsk, Hin, ys);
    k_merge_ln<<<B_ * L_, 192, 0, stream>>>(ys, gw, gb, out);
}

// Round 2
// 406.636 us; speedup vs baseline: 1.1764x; 1.1764x over previous
//
#include <hip/hip_runtime.h>
#include <hip/hip_bf16.h>

#define B_  8
#define D_  192
#define H_  64
#define W_  64
#define L_  4096
#define K_  4
#define N_  16
#define R_  6
#define C_  38   // R + 2N
#define CP  40   // padded x_dbl row (floats)
#define CL_ 64   // scan chunk length
#define NC_ 64   // number of chunks (L_/CL_)

using bf16 = __hip_bfloat16;

static __device__ __forceinline__ float softplus_f(float x) {
    return fmaxf(x, 0.f) + __logf(1.f + __expf(-fabsf(x)));
}
static __device__ __forceinline__ float bflo(unsigned u) {
    return __uint_as_float(u << 16);
}
static __device__ __forceinline__ float bfhi(unsigned u) {
    return __uint_as_float(u & 0xffff0000u);
}

// ---------------------------------------------------------------------------
// Kernel 1: transpose x (B,D,L) -> xp0 (B,L,D) row-major scan order and
// xp1 (B,L1,D) col-major order (l1 = w*H + h), plus bf16 copies for k_proj.
// ---------------------------------------------------------------------------
__global__ __launch_bounds__(256) void k_transpose(const float* __restrict__ x,
                                                   float* __restrict__ xp0,
                                                   float* __restrict__ xp1,
                                                   bf16* __restrict__ xp0b,
                                                   bf16* __restrict__ xp1b) {
    __shared__ float tile[32][33];
    int bi = blockIdx.x;
    int pg = bi & 127;          // L/32 tiles
    int dg = (bi >> 7) % 6;     // D/32 tiles
    int b  = bi / (128 * 6);
    int tx = threadIdx.x & 31;
    int ty = threadIdx.x >> 5;  // 0..7
    size_t xbase = (size_t)b * D_ * L_;
    #pragma unroll
    for (int i = 0; i < 4; i++) {
        int d = dg * 32 + ty + i * 8;
        tile[ty + i * 8][tx] = x[xbase + (size_t)d * L_ + pg * 32 + tx];
    }
    __syncthreads();
    #pragma unroll
    for (int i = 0; i < 4; i++) {
        int p = pg * 32 + ty + i * 8;
        float v = tile[tx][ty + i * 8];
        bf16 vb = __float2bfloat16(v);
        int d = dg * 32 + tx;
        size_t o0 = ((size_t)b * L_ + p) * D_ + d;
        xp0[o0] = v;  xp0b[o0] = vb;
        int hh = p >> 6, ww = p & 63;
        int r = ww * 64 + hh;   // l1 index
        size_t o1 = ((size_t)b * L_ + r) * D_ + d;
        xp1[o1] = v;  xp1b[o1] = vb;
    }
}

// ---------------------------------------------------------------------------
// Kernel 2: projection x_dbl[b,k,l,c] = sum_d xs[b,k,d,l] * W[k,c,d]
// 128-l tile staged in LDS (bf16); 256 threads = (c-half, l); c-half is
// wave-uniform and readfirstlane'd so W loads become s_load.
// ---------------------------------------------------------------------------
__global__ __launch_bounds__(256) void k_proj(const bf16* __restrict__ xp0b,
                                              const bf16* __restrict__ xp1b,
                                              const float* __restrict__ Wp,   // (K,38,192)
                                              float* __restrict__ xdbl) {     // (B,K,L,CP)
    __shared__ __align__(16) unsigned short xt[128 * 200]; // stride 200 bf16
    int blk  = blockIdx.x;
    int tile = blk & 31;            // L/128 tiles
    int bk   = blk >> 5;
    int k    = bk & 3;
    int b    = bk >> 2;
    const bf16* xpb = (k & 1) ? xp1b : xp0b;
    int g0 = (k < 2) ? tile * 128 : (L_ - 128 - tile * 128);

    // stage 128 rows x 192 bf16 (coalesced 16B chunks)
    const uint4* src = (const uint4*)(xpb + ((size_t)b * L_ + g0) * D_);
    for (int i = threadIdx.x; i < 3072; i += 256) {
        uint4 v = src[i];
        int row = i / 24, cg = i % 24;
        *((uint4*)(xt + row * 200 + cg * 8)) = v;
    }
    __syncthreads();

    int tl = threadIdx.x & 127;
    int ch = __builtin_amdgcn_readfirstlane((int)(threadIdx.x >> 7)); // 0/1
    int l  = tile * 128 + tl;
    int lrow = (k < 2) ? tl : (127 - tl);

    const unsigned short* xrow = xt + lrow * 200;
    const float* Wc = Wp + ((size_t)k * C_ + (size_t)ch * 19) * D_;

    float acc[19];
    #pragma unroll
    for (int ci = 0; ci < 19; ci++) acc[ci] = 0.f;

    for (int kk = 0; kk < 24; kk++) {       // 24 groups of 8 channels
        uint4 xv = *((const uint4*)(xrow + kk * 8));
        float xf0 = bflo(xv.x), xf1 = bfhi(xv.x);
        float xf2 = bflo(xv.y), xf3 = bfhi(xv.y);
        float xf4 = bflo(xv.z), xf5 = bfhi(xv.z);
        float xf6 = bflo(xv.w), xf7 = bfhi(xv.w);
        #pragma unroll
        for (int ci = 0; ci < 19; ci++) {
            const float* w = Wc + ci * D_ + kk * 8;
            float4 w0 = *((const float4*)w);
            float4 w1 = *((const float4*)(w + 4));
            acc[ci] = fmaf(xf0, w0.x, acc[ci]); acc[ci] = fmaf(xf1, w0.y, acc[ci]);
            acc[ci] = fmaf(xf2, w0.z, acc[ci]); acc[ci] = fmaf(xf3, w0.w, acc[ci]);
            acc[ci] = fmaf(xf4, w1.x, acc[ci]); acc[ci] = fmaf(xf5, w1.y, acc[ci]);
            acc[ci] = fmaf(xf6, w1.z, acc[ci]); acc[ci] = fmaf(xf7, w1.w, acc[ci]);
        }
    }
    float* orow = xdbl + ((size_t)bk * L_ + l) * CP + ch * 19;
    #pragma unroll
    for (int ci = 0; ci < 19; ci++) orow[ci] = acc[ci];
}

// ---------------------------------------------------------------------------
// Kernel 3 (pass 1): per-chunk partial scan from h=0, xdbl chunk in LDS.
// ---------------------------------------------------------------------------
__global__ __launch_bounds__(192) void k_pass1(const float* __restrict__ xdbl,
                                               const float* __restrict__ xp0,
                                               const float* __restrict__ xp1,
                                               const float* __restrict__ dtw,   // (K,D,R)
                                               const float* __restrict__ dtb,   // (K,D)
                                               const float* __restrict__ Alog,  // (K*D,N)
                                               bf16* __restrict__ Pst,
                                               bf16* __restrict__ Hloc) {
    __shared__ __align__(16) float xd[CL_ * CP];   // 10.25 KB
    int blk = blockIdx.x;
    int c   = blk & (NC_ - 1);
    int bk  = blk >> 6;
    int k   = bk & 3;
    int b   = bk >> 2;
    int d   = threadIdx.x;

    const float* srow = xdbl + ((size_t)bk * L_ + c * CL_) * CP;
    for (int i = threadIdx.x; i < CL_ * CP / 4; i += 192)
        ((float4*)xd)[i] = ((const float4*)srow)[i];

    float A2[N_];     // A * log2(e), for exp2
    #pragma unroll
    for (int n = 0; n < N_; n++)
        A2[n] = -__expf(Alog[((size_t)(k * D_ + d)) * N_ + n]) * 1.44269504f;
    float wr[R_];
    #pragma unroll
    for (int r = 0; r < R_; r++) wr[r] = dtw[(k * D_ + d) * R_ + r];
    float bias = dtb[k * D_ + d];
    const float* xp = (k & 1) ? xp1 : xp0;
    __syncthreads();

    float h[N_];
    #pragma unroll
    for (int n = 0; n < N_; n++) h[n] = 0.f;
    float S = 0.f;

    for (int s = 0; s < CL_; s++) {
        const float4* r4 = (const float4*)(xd + s * CP);
        float4 q0 = r4[0], q1 = r4[1], q2 = r4[2], q3 = r4[3], q4 = r4[4], q5 = r4[5];
        float dpre = bias + wr[0]*q0.x + wr[1]*q0.y + wr[2]*q0.z + wr[3]*q0.w
                          + wr[4]*q1.x + wr[5]*q1.y;
        float delta = softplus_f(dpre);
        int l  = c * CL_ + s;
        int lu = (k < 2) ? l : (L_ - 1 - l);
        float u  = xp[((size_t)b * L_ + lu) * D_ + d];
        float du = delta * u;
        S += delta;
        float Bv[N_] = {q1.z,q1.w,q2.x,q2.y,q2.z,q2.w,q3.x,q3.y,
                        q3.z,q3.w,q4.x,q4.y,q4.z,q4.w,q5.x,q5.y};
        #pragma unroll
        for (int n = 0; n < N_; n++) {
            float dA = __builtin_amdgcn_exp2f(delta * A2[n]);
            h[n] = fmaf(dA, h[n], du * Bv[n]);
        }
    }
    size_t o = ((size_t)blk * D_ + d) * N_;   // blk == bk*NC_ + c
    #pragma unroll
    for (int n = 0; n < N_; n++) {
        Pst[o + n]  = __float2bfloat16(__builtin_amdgcn_exp2f(A2[n] * S));
        Hloc[o + n] = __float2bfloat16(h[n]);
    }
}

// ---------------------------------------------------------------------------
// Kernel 4 (pass 2): chunk-prefix scan over NC_ chunks per (b,k,d,n).
// ---------------------------------------------------------------------------
__global__ __launch_bounds__(256) void k_pass2(const bf16* __restrict__ Pst,
                                               const bf16* __restrict__ Hloc,
                                               bf16* __restrict__ Hin) {
    int idx = blockIdx.x * 256 + threadIdx.x;   // over B*K*D*N
    int bk  = idx / (D_ * N_);
    int dn  = idx % (D_ * N_);
    float hh = 0.f;
    for (int c = 0; c < NC_; c++) {
        size_t o = ((size_t)bk * NC_ + c) * (D_ * N_) + dn;
        Hin[o] = __float2bfloat16(hh);
        hh = __bfloat162float(Pst[o]) * hh + __bfloat162float(Hloc[o]);
    }
}

// ---------------------------------------------------------------------------
// Kernel 5 (pass 3): recompute chunk scan with true h0, emit
// ys[b,k,l,d] = C_l . h_l + u * Ds   (bf16). xdbl chunk in LDS.
// ---------------------------------------------------------------------------
__global__ __launch_bounds__(192) void k_pass3(const float* __restrict__ xdbl,
                                               const float* __restrict__ xp0,
                                               const float* __restrict__ xp1,
                                               const float* __restrict__ dtw,
                                               const float* __restrict__ dtb,
                                               const float* __restrict__ Alog,
                                               const float* __restrict__ Dsk,  // (K*D,)
                                               const bf16* __restrict__ Hin,
                                               bf16* __restrict__ ys) {        // (B,K,L,D)
    __shared__ __align__(16) float xd[CL_ * CP];
    int blk = blockIdx.x;
    int c   = blk & (NC_ - 1);
    int bk  = blk >> 6;
    int k   = bk & 3;
    int b   = bk >> 2;
    int d   = threadIdx.x;

    const float* srow = xdbl + ((size_t)bk * L_ + c * CL_) * CP;
    for (int i = threadIdx.x; i < CL_ * CP / 4; i += 192)
        ((float4*)xd)[i] = ((const float4*)srow)[i];

    float A2[N_];
    #pragma unroll
    for (int n = 0; n < N_; n++)
        A2[n] = -__expf(Alog[((size_t)(k * D_ + d)) * N_ + n]) * 1.44269504f;
    float wr[R_];
    #pragma unroll
    for (int r = 0; r < R_; r++) wr[r] = dtw[(k * D_ + d) * R_ + r];
    float bias = dtb[k * D_ + d];
    float DsV  = Dsk[k * D_ + d];
    const float* xp = (k & 1) ? xp1 : xp0;

    float h[N_];
    size_t o = ((size_t)blk * D_ + d) * N_;
    #pragma unroll
    for (int n = 0; n < N_; n++) h[n] = __bfloat162float(Hin[o + n]);
    __syncthreads();

    for (int s = 0; s < CL_; s++) {
        const float4* r4 = (const float4*)(xd + s * CP);
        float4 q0 = r4[0], q1 = r4[1], q2 = r4[2], q3 = r4[3], q4 = r4[4];
        float4 q5 = r4[5], q6 = r4[6], q7 = r4[7], q8 = r4[8], q9 = r4[9];
        float dpre = bias + wr[0]*q0.x + wr[1]*q0.y + wr[2]*q0.z + wr[3]*q0.w
                          + wr[4]*q1.x + wr[5]*q1.y;
        float delta = softplus_f(dpre);
        int l  = c * CL_ + s;
        int lu = (k < 2) ? l : (L_ - 1 - l);
        float u  = xp[((size_t)b * L_ + lu) * D_ + d];
        float du = delta * u;
        float Bv[N_] = {q1.z,q1.w,q2.x,q2.y,q2.z,q2.w,q3.x,q3.y,
                        q3.z,q3.w,q4.x,q4.y,q4.z,q4.w,q5.x,q5.y};
        float Cv[N_] = {q5.z,q5.w,q6.x,q6.y,q6.z,q6.w,q7.x,q7.y,
                        q7.z,q7.w,q8.x,q8.y,q8.z,q8.w,q9.x,q9.y};
        float y = 0.f;
        #pragma unroll
        for (int n = 0; n < N_; n++) {
            float dA = __builtin_amdgcn_exp2f(delta * A2[n]);
            h[n] = fmaf(dA, h[n], du * Bv[n]);
            y = fmaf(h[n], Cv[n], y);
        }
        ys[((size_t)bk * L_ + l) * D_ + d] = __float2bfloat16(y + u * DsV);
    }
}

// ---------------------------------------------------------------------------
// Kernel 6: cross-merge (4 directions) + LayerNorm over D, output (B,H,W,D)
// ---------------------------------------------------------------------------
__global__ __launch_bounds__(192) void k_merge_ln(const bf16* __restrict__ ys,
                                                  const float* __restrict__ gw,
                                                  const float* __restrict__ gb,
                                                  float* __restrict__ out) {
    int p = blockIdx.x & (L_ - 1);
    int b = blockIdx.x >> 12;     // L_ = 4096
    int d = threadIdx.x;
    int hh = p >> 6, ww = p & 63;
    int l1 = ww * 64 + hh;
    size_t base = (size_t)b * K_ * L_ * D_;
    float v = __bfloat162float(ys[base + ((size_t)0 * L_ + p) * D_ + d])
            + __bfloat162float(ys[base + ((size_t)2 * L_ + (L_ - 1 - p)) * D_ + d])
            + __bfloat162float(ys[base + ((size_t)1 * L_ + l1) * D_ + d])
            + __bfloat162float(ys[base + ((size_t)3 * L_ + (L_ - 1 - l1)) * D_ + d]);
    float s1 = v, s2 = v * v;
    #pragma unroll
    for (int off = 32; off; off >>= 1) {
        s1 += __shfl_down(s1, off);
        s2 += __shfl_down(s2, off);
    }
    __shared__ float aS[3], aQ[3];
    int wid = d >> 6, lane = d & 63;
    if (lane == 0) { aS[wid] = s1; aQ[wid] = s2; }
    __syncthreads();
    float ts1 = aS[0] + aS[1] + aS[2];
    float ts2 = aQ[0] + aQ[1] + aQ[2];
    float mean = ts1 * (1.f / 192.f);
    float var  = ts2 * (1.f / 192.f) - mean * mean;
    float inv  = rsqrtf(var + 1e-5f);
    out[((size_t)b * L_ + p) * D_ + d] = (v - mean) * inv * gw[d] + gb[d];
}

// ---------------------------------------------------------------------------
extern "C" void kernel_launch(void* const* d_in, const int* in_sizes, int n_in,
                              void* d_out, int out_size, void* d_ws, size_t ws_size,
                              hipStream_t stream) {
    const float* x    = (const float*)d_in[0];
    const float* Wp   = (const float*)d_in[1];
    const float* dtw  = (const float*)d_in[2];
    const float* dtb  = (const float*)d_in[3];
    const float* Alog = (const float*)d_in[4];
    const float* Dsk  = (const float*)d_in[5];
    const float* gw   = (const float*)d_in[6];
    const float* gb   = (const float*)d_in[7];
    float* out = (float*)d_out;

    char* ws = (char*)d_ws;
    const size_t S1  = (size_t)B_ * L_ * D_ * 4;            // 25.2 MB (xp0/xp1)
    const size_t S1b = (size_t)B_ * L_ * D_ * 2;            // 12.6 MB (xp0b/xp1b)
    const size_t Sx  = (size_t)B_ * K_ * L_ * CP * 4;       // 21.0 MB (xdbl)
    const size_t Ss  = (size_t)B_ * K_ * NC_ * D_ * N_ * 2; // 12.6 MB (P/Hloc/Hin)
    char* p = ws;
    float* xp0  = (float*)p;  p += S1;
    float* xp1  = (float*)p;  p += S1;
    bf16*  xp0b = (bf16*)p;   p += S1b;
    bf16*  xp1b = (bf16*)p;   p += S1b;
    float* xdbl = (float*)p;  p += Sx;
    bf16*  Pst  = (bf16*)p;   p += Ss;
    bf16*  Hloc = (bf16*)p;   p += Ss;
    bf16*  Hin  = (bf16*)p;   p += Ss;
    bf16*  ys   = (bf16*)p;   // 50.3 MB; total ~185 MB

    k_transpose<<<B_ * 6 * 128, 256, 0, stream>>>(x, xp0, xp1, xp0b, xp1b);
    k_proj<<<B_ * K_ * (L_ / 128), 256, 0, stream>>>(xp0b, xp1b, Wp, xdbl);
    k_pass1<<<B_ * K_ * NC_, 192, 0, stream>>>(xdbl, xp0, xp1, dtw, dtb, Alog, Pst, Hloc);
    k_pass2<<<(B_ * K_ * D_ * N_) / 256, 256, 0, stream>>>(Pst, Hloc, Hin);
    k_pass3<<<B_ * K_ * NC_, 192, 0, stream>>>(xdbl, xp0, xp1, dtw, dtb, Alog, Dsk, Hin, ys);
    k_merge_ln<<<B_ * L_, 192, 0, stream>>>(ys, gw, gb, out);
}

// Round 3
// 349.072 us; speedup vs baseline: 1.3703x; 1.1649x over previous
//
#include <hip/hip_runtime.h>
#include <hip/hip_bf16.h>

#define B_  8
#define D_  192
#define H_  64
#define W_  64
#define L_  4096
#define K_  4
#define N_  16
#define R_  6
#define C_  38   // R + 2N
#define CP  40   // padded x_dbl row (floats)
#define CL_ 64   // scan chunk length
#define NC_ 64   // number of chunks (L_/CL_)

using bf16 = __hip_bfloat16;

static __device__ __forceinline__ float softplus_f(float x) {
    return fmaxf(x, 0.f) + __logf(1.f + __expf(-fabsf(x)));
}
static __device__ __forceinline__ float bflo(unsigned u) {
    return __uint_as_float(u << 16);
}
static __device__ __forceinline__ float bfhi(unsigned u) {
    return __uint_as_float(u & 0xffff0000u);
}

// ---------------------------------------------------------------------------
// Kernel 1: transpose x (B,D,L) -> xp0 (B,L,D) row-major scan order and
// xp1 (B,L1,D) col-major order (l1 = w*H + h), plus bf16 copies for k_proj.
// ---------------------------------------------------------------------------
__global__ __launch_bounds__(256) void k_transpose(const float* __restrict__ x,
                                                   float* __restrict__ xp0,
                                                   float* __restrict__ xp1,
                                                   bf16* __restrict__ xp0b,
                                                   bf16* __restrict__ xp1b) {
    __shared__ float tile[32][33];
    int bi = blockIdx.x;
    int pg = bi & 127;          // L/32 tiles
    int dg = (bi >> 7) % 6;     // D/32 tiles
    int b  = bi / (128 * 6);
    int tx = threadIdx.x & 31;
    int ty = threadIdx.x >> 5;  // 0..7
    size_t xbase = (size_t)b * D_ * L_;
    #pragma unroll
    for (int i = 0; i < 4; i++) {
        int d = dg * 32 + ty + i * 8;
        tile[ty + i * 8][tx] = x[xbase + (size_t)d * L_ + pg * 32 + tx];
    }
    __syncthreads();
    #pragma unroll
    for (int i = 0; i < 4; i++) {
        int p = pg * 32 + ty + i * 8;
        float v = tile[tx][ty + i * 8];
        bf16 vb = __float2bfloat16(v);
        int d = dg * 32 + tx;
        size_t o0 = ((size_t)b * L_ + p) * D_ + d;
        xp0[o0] = v;  xp0b[o0] = vb;
        int hh = p >> 6, ww = p & 63;
        int r = ww * 64 + hh;   // l1 index
        size_t o1 = ((size_t)b * L_ + r) * D_ + d;
        xp1[o1] = v;  xp1b[o1] = vb;
    }
}

// ---------------------------------------------------------------------------
// Kernel 2: projection x_dbl[b,k,l,c] = sum_d xs[b,k,d,l] * W[k,c,d]
// Block = 64 positions x 38 channels. Wave = channel-quarter (wave-uniform,
// W loads scalarize to s_load, f32 precision); lane = position (x chunk from
// LDS, one b128 per kk-group). 24 waves/CU.
// ---------------------------------------------------------------------------
__global__ __launch_bounds__(256) void k_proj(const bf16* __restrict__ xp0b,
                                              const bf16* __restrict__ xp1b,
                                              const float* __restrict__ Wp,   // (K,38,192)
                                              float* __restrict__ xdbl) {     // (B,K,L,CP)
    __shared__ __align__(16) unsigned short xt[64 * 200]; // 25.6 KB, stride 200 bf16
    int blk  = blockIdx.x;
    int tile = blk & 63;            // L/64 tiles
    int bk   = blk >> 6;
    int k    = bk & 3;
    int b    = bk >> 2;
    const bf16* xpb = (k & 1) ? xp1b : xp0b;
    int g0 = (k < 2) ? tile * 64 : (L_ - 64 - tile * 64);

    // stage 64 rows x 192 bf16, coalesced
    const uint4* src = (const uint4*)(xpb + ((size_t)b * L_ + g0) * D_);
    for (int i = threadIdx.x; i < 1536; i += 256) {
        uint4 v = src[i];
        int row = i / 24, cg = i % 24;
        *((uint4*)(xt + row * 200 + cg * 8)) = v;
    }
    __syncthreads();

    int lane = threadIdx.x & 63;
    int wv   = __builtin_amdgcn_readfirstlane((int)(threadIdx.x >> 6)); // 0..3
    int c0   = wv * 10;
    int l    = tile * 64 + lane;
    int lrow = (k < 2) ? lane : (63 - lane);

    const unsigned short* xrow = xt + lrow * 200;

    float acc[10];
    #pragma unroll
    for (int ci = 0; ci < 10; ci++) acc[ci] = 0.f;

    for (int kk = 0; kk < 24; kk++) {       // 24 groups of 8 d-channels
        uint4 xv = *((const uint4*)(xrow + kk * 8));
        float xf0 = bflo(xv.x), xf1 = bfhi(xv.x);
        float xf2 = bflo(xv.y), xf3 = bfhi(xv.y);
        float xf4 = bflo(xv.z), xf5 = bfhi(xv.z);
        float xf6 = bflo(xv.w), xf7 = bfhi(xv.w);
        #pragma unroll
        for (int ci = 0; ci < 10; ci++) {
            int c = c0 + ci; if (c > 37) c = 37;     // wave 3: dup of c37 (harmless)
            const float* w = Wp + ((size_t)k * C_ + c) * D_ + kk * 8;  // uniform -> s_load
            float4 w0 = *((const float4*)w);
            float4 w1 = *((const float4*)(w + 4));
            acc[ci] = fmaf(xf0, w0.x, acc[ci]); acc[ci] = fmaf(xf1, w0.y, acc[ci]);
            acc[ci] = fmaf(xf2, w0.z, acc[ci]); acc[ci] = fmaf(xf3, w0.w, acc[ci]);
            acc[ci] = fmaf(xf4, w1.x, acc[ci]); acc[ci] = fmaf(xf5, w1.y, acc[ci]);
            acc[ci] = fmaf(xf6, w1.z, acc[ci]); acc[ci] = fmaf(xf7, w1.w, acc[ci]);
        }
    }
    float* orow = xdbl + ((size_t)bk * L_ + l) * CP;
    #pragma unroll
    for (int ci = 0; ci < 10; ci++) {
        int c = c0 + ci; if (c > 37) c = 37;
        orow[c] = acc[ci];
    }
}

// ---------------------------------------------------------------------------
// Kernel 3 (pass 1): per-chunk partial scan from h=0. xdbl rows read via
// block-uniform addresses -> compiler scalarizes to s_load (no LDS, no VMEM
// on the broadcast path). Stores chunk decay P and local end-state Hloc.
// ---------------------------------------------------------------------------
__global__ __launch_bounds__(192) void k_pass1(const float* __restrict__ xdbl,
                                               const float* __restrict__ xp0,
                                               const float* __restrict__ xp1,
                                               const float* __restrict__ dtw,   // (K,D,R)
                                               const float* __restrict__ dtb,   // (K,D)
                                               const float* __restrict__ Alog,  // (K*D,N)
                                               bf16* __restrict__ Pst,
                                               bf16* __restrict__ Hloc) {
    int blk = blockIdx.x;
    int c   = blk & (NC_ - 1);
    int bk  = blk >> 6;
    int k   = bk & 3;
    int b   = bk >> 2;
    int d   = threadIdx.x;

    float A2[N_];     // A * log2(e), for exp2
    #pragma unroll
    for (int n = 0; n < N_; n++)
        A2[n] = -__expf(Alog[((size_t)(k * D_ + d)) * N_ + n]) * 1.44269504f;
    float wr[R_];
    #pragma unroll
    for (int r = 0; r < R_; r++) wr[r] = dtw[(k * D_ + d) * R_ + r];
    float bias = dtb[k * D_ + d];
    const float* xp = (k & 1) ? xp1 : xp0;

    float h[N_];
    #pragma unroll
    for (int n = 0; n < N_; n++) h[n] = 0.f;
    float S = 0.f;
    const float* rb = xdbl + ((size_t)bk * L_ + c * CL_) * CP;

    #pragma unroll 2
    for (int s = 0; s < CL_; s++) {
        const float4* r4 = (const float4*)(rb + s * CP);   // block-uniform
        float4 q0 = r4[0], q1 = r4[1], q2 = r4[2], q3 = r4[3], q4 = r4[4], q5 = r4[5];
        float dpre = bias + wr[0]*q0.x + wr[1]*q0.y + wr[2]*q0.z + wr[3]*q0.w
                          + wr[4]*q1.x + wr[5]*q1.y;
        float delta = softplus_f(dpre);
        int l  = c * CL_ + s;
        int lu = (k < 2) ? l : (L_ - 1 - l);
        float u  = xp[((size_t)b * L_ + lu) * D_ + d];
        float du = delta * u;
        S += delta;
        float Bv[N_] = {q1.z,q1.w,q2.x,q2.y,q2.z,q2.w,q3.x,q3.y,
                        q3.z,q3.w,q4.x,q4.y,q4.z,q4.w,q5.x,q5.y};
        #pragma unroll
        for (int n = 0; n < N_; n++) {
            float dA = __builtin_amdgcn_exp2f(delta * A2[n]);
            h[n] = fmaf(dA, h[n], du * Bv[n]);
        }
    }
    size_t o = ((size_t)blk * D_ + d) * N_;   // blk == bk*NC_ + c
    #pragma unroll
    for (int n = 0; n < N_; n++) {
        Pst[o + n]  = __float2bfloat16(__builtin_amdgcn_exp2f(A2[n] * S));
        Hloc[o + n] = __float2bfloat16(h[n]);
    }
}

// ---------------------------------------------------------------------------
// Kernel 4 (pass 2): chunk-prefix scan over NC_ chunks per (b,k,d,n).
// ---------------------------------------------------------------------------
__global__ __launch_bounds__(256) void k_pass2(const bf16* __restrict__ Pst,
                                               const bf16* __restrict__ Hloc,
                                               bf16* __restrict__ Hin) {
    int idx = blockIdx.x * 256 + threadIdx.x;   // over B*K*D*N
    int bk  = idx / (D_ * N_);
    int dn  = idx % (D_ * N_);
    float hh = 0.f;
    for (int c = 0; c < NC_; c++) {
        size_t o = ((size_t)bk * NC_ + c) * (D_ * N_) + dn;
        Hin[o] = __float2bfloat16(hh);
        hh = __bfloat162float(Pst[o]) * hh + __bfloat162float(Hloc[o]);
    }
}

// ---------------------------------------------------------------------------
// Kernel 5 (pass 3): recompute chunk scan with true h0, emit
// ys[b,k,l,d] = C_l . h_l + u * Ds (bf16). xdbl rows via scalar loads.
// ---------------------------------------------------------------------------
__global__ __launch_bounds__(192) void k_pass3(const float* __restrict__ xdbl,
                                               const float* __restrict__ xp0,
                                               const float* __restrict__ xp1,
                                               const float* __restrict__ dtw,
                                               const float* __restrict__ dtb,
                                               const float* __restrict__ Alog,
                                               const float* __restrict__ Dsk,  // (K*D,)
                                               const bf16* __restrict__ Hin,
                                               bf16* __restrict__ ys) {        // (B,K,L,D)
    int blk = blockIdx.x;
    int c   = blk & (NC_ - 1);
    int bk  = blk >> 6;
    int k   = bk & 3;
    int b   = bk >> 2;
    int d   = threadIdx.x;

    float A2[N_];
    #pragma unroll
    for (int n = 0; n < N_; n++)
        A2[n] = -__expf(Alog[((size_t)(k * D_ + d)) * N_ + n]) * 1.44269504f;
    float wr[R_];
    #pragma unroll
    for (int r = 0; r < R_; r++) wr[r] = dtw[(k * D_ + d) * R_ + r];
    float bias = dtb[k * D_ + d];
    float DsV  = Dsk[k * D_ + d];
    const float* xp = (k & 1) ? xp1 : xp0;

    float h[N_];
    size_t o = ((size_t)blk * D_ + d) * N_;
    #pragma unroll
    for (int n = 0; n < N_; n++) h[n] = __bfloat162float(Hin[o + n]);

    const float* rb = xdbl + ((size_t)bk * L_ + c * CL_) * CP;

    #pragma unroll 2
    for (int s = 0; s < CL_; s++) {
        const float4* r4 = (const float4*)(rb + s * CP);   // block-uniform
        float4 q0 = r4[0], q1 = r4[1], q2 = r4[2], q3 = r4[3], q4 = r4[4];
        float4 q5 = r4[5], q6 = r4[6], q7 = r4[7], q8 = r4[8], q9 = r4[9];
        float dpre = bias + wr[0]*q0.x + wr[1]*q0.y + wr[2]*q0.z + wr[3]*q0.w
                          + wr[4]*q1.x + wr[5]*q1.y;
        float delta = softplus_f(dpre);
        int l  = c * CL_ + s;
        int lu = (k < 2) ? l : (L_ - 1 - l);
        float u  = xp[((size_t)b * L_ + lu) * D_ + d];
        float du = delta * u;
        float Bv[N_] = {q1.z,q1.w,q2.x,q2.y,q2.z,q2.w,q3.x,q3.y,
                        q3.z,q3.w,q4.x,q4.y,q4.z,q4.w,q5.x,q5.y};
        float Cv[N_] = {q5.z,q5.w,q6.x,q6.y,q6.z,q6.w,q7.x,q7.y,
                        q7.z,q7.w,q8.x,q8.y,q8.z,q8.w,q9.x,q9.y};
        float y = 0.f;
        #pragma unroll
        for (int n = 0; n < N_; n++) {
            float dA = __builtin_amdgcn_exp2f(delta * A2[n]);
            h[n] = fmaf(dA, h[n], du * Bv[n]);
            y = fmaf(h[n], Cv[n], y);
        }
        ys[((size_t)bk * L_ + l) * D_ + d] = __float2bfloat16(y + u * DsV);
    }
}

// ---------------------------------------------------------------------------
// Kernel 6: cross-merge (4 directions) + LayerNorm over D, output (B,H,W,D)
// ---------------------------------------------------------------------------
__global__ __launch_bounds__(192) void k_merge_ln(const bf16* __restrict__ ys,
                                                  const float* __restrict__ gw,
                                                  const float* __restrict__ gb,
                                                  float* __restrict__ out) {
    int p = blockIdx.x & (L_ - 1);
    int b = blockIdx.x >> 12;     // L_ = 4096
    int d = threadIdx.x;
    int hh = p >> 6, ww = p & 63;
    int l1 = ww * 64 + hh;
    size_t base = (size_t)b * K_ * L_ * D_;
    float v = __bfloat162float(ys[base + ((size_t)0 * L_ + p) * D_ + d])
            + __bfloat162float(ys[base + ((size_t)2 * L_ + (L_ - 1 - p)) * D_ + d])
            + __bfloat162float(ys[base + ((size_t)1 * L_ + l1) * D_ + d])
            + __bfloat162float(ys[base + ((size_t)3 * L_ + (L_ - 1 - l1)) * D_ + d]);
    float s1 = v, s2 = v * v;
    #pragma unroll
    for (int off = 32; off; off >>= 1) {
        s1 += __shfl_down(s1, off);
        s2 += __shfl_down(s2, off);
    }
    __shared__ float aS[3], aQ[3];
    int wid = d >> 6, lane = d & 63;
    if (lane == 0) { aS[wid] = s1; aQ[wid] = s2; }
    __syncthreads();
    float ts1 = aS[0] + aS[1] + aS[2];
    float ts2 = aQ[0] + aQ[1] + aQ[2];
    float mean = ts1 * (1.f / 192.f);
    float var  = ts2 * (1.f / 192.f) - mean * mean;
    float inv  = rsqrtf(var + 1e-5f);
    out[((size_t)b * L_ + p) * D_ + d] = (v - mean) * inv * gw[d] + gb[d];
}

// ---------------------------------------------------------------------------
extern "C" void kernel_launch(void* const* d_in, const int* in_sizes, int n_in,
                              void* d_out, int out_size, void* d_ws, size_t ws_size,
                              hipStream_t stream) {
    const float* x    = (const float*)d_in[0];
    const float* Wp   = (const float*)d_in[1];
    const float* dtw  = (const float*)d_in[2];
    const float* dtb  = (const float*)d_in[3];
    const float* Alog = (const float*)d_in[4];
    const float* Dsk  = (const float*)d_in[5];
    const float* gw   = (const float*)d_in[6];
    const float* gb   = (const float*)d_in[7];
    float* out = (float*)d_out;

    char* ws = (char*)d_ws;
    const size_t S1  = (size_t)B_ * L_ * D_ * 4;            // 25.2 MB (xp0/xp1)
    const size_t S1b = (size_t)B_ * L_ * D_ * 2;            // 12.6 MB (xp0b/xp1b)
    const size_t Sx  = (size_t)B_ * K_ * L_ * CP * 4;       // 21.0 MB (xdbl)
    const size_t Ss  = (size_t)B_ * K_ * NC_ * D_ * N_ * 2; // 12.6 MB (P/Hloc/Hin)
    char* p = ws;
    float* xp0  = (float*)p;  p += S1;
    float* xp1  = (float*)p;  p += S1;
    bf16*  xp0b = (bf16*)p;   p += S1b;
    bf16*  xp1b = (bf16*)p;   p += S1b;
    float* xdbl = (float*)p;  p += Sx;
    bf16*  Pst  = (bf16*)p;   p += Ss;
    bf16*  Hloc = (bf16*)p;   p += Ss;
    bf16*  Hin  = (bf16*)p;   p += Ss;
    bf16*  ys   = (bf16*)p;   // 50.3 MB; total ~185 MB

    k_transpose<<<B_ * 6 * 128, 256, 0, stream>>>(x, xp0, xp1, xp0b, xp1b);
    k_proj<<<B_ * K_ * (L_ / 64), 256, 0, stream>>>(xp0b, xp1b, Wp, xdbl);
    k_pass1<<<B_ * K_ * NC_, 192, 0, stream>>>(xdbl, xp0, xp1, dtw, dtb, Alog, Pst, Hloc);
    k_pass2<<<(B_ * K_ * D_ * N_) / 256, 256, 0, stream>>>(Pst, Hloc, Hin);
    k_pass3<<<B_ * K_ * NC_, 192, 0, stream>>>(xdbl, xp0, xp1, dtw, dtb, Alog, Dsk, Hin, ys);
    k_merge_ln<<<B_ * L_, 192, 0, stream>>>(ys, gw, gb, out);
}